// Round 1
// baseline (1178.761 us; speedup 1.0000x reference)
//
#include <hip/hip_runtime.h>

#define NUM_TABLES 8
#define BUCKETS 524288          // 2^19
#define EMBED_DIM 64
#define BB 8
#define TT 4096
#define POS_PER_BLOCK 32
#define LOOKBACK 128

__global__ __launch_bounds__(256) void hashtables_kernel(
    const int* __restrict__ tokens,      // [B, T] (values < 32000, fit i32)
    const float* __restrict__ tables,    // [8, 524288, 64] f32
    float* __restrict__ out)             // [B, T, 512] f32
{
    __shared__ int s_tok[LOOKBACK + POS_PER_BLOCK];        // 160 ints
    __shared__ unsigned s_idx[POS_PER_BLOCK][NUM_TABLES];  // 32x8 bucket ids

    const int tid = threadIdx.x;
    const int b     = blockIdx.x >> 7;    // / (T/POS_PER_BLOCK) = /128
    const int chunk = blockIdx.x & 127;
    const int t0    = chunk * POS_PER_BLOCK;

    // ---- stage tokens t0-128 .. t0+31 (zero-pad before row start) ----
    if (tid < LOOKBACK + POS_PER_BLOCK) {
        int t = t0 - LOOKBACK + tid;
        s_tok[tid] = (t >= 0) ? tokens[b * TT + t] : 0;
    }
    __syncthreads();

    // ---- hash phase: one thread per (position, table) ----
    {
        const int table = tid >> 5;      // 0..7  (wave-pairs of tables)
        const int p     = tid & 31;      // position within block
        const int w     = 1 << table;    // window size 1..128
        const int base  = LOOKBACK + p;  // s_tok index of position t
        unsigned h = 0;
        // primes as literals via full inner unroll (j%8 is compile-time)
        for (int jo = 0; jo < 16; ++jo) {
#pragma unroll
            for (int ji = 0; ji < 8; ++ji) {
                const int j = jo * 8 + ji;
                constexpr unsigned PR[8] = {2654435761u, 2246822519u, 3266489917u,
                                            2028178513u, 1220703125u, 1610612741u,
                                            805306457u,  402653189u};
                if (j < w) h ^= (unsigned)s_tok[base - 1 - j] * PR[ji];
            }
            if ((jo + 1) * 8 >= w) break;
        }
        s_idx[p][table] = h & (BUCKETS - 1);   // h % 2^19 == low 19 bits of XOR
    }
    __syncthreads();

    // ---- gather phase: 32 pos * 8 tables * 16 float4 = 4096 float4/block ----
    const float4* __restrict__ tab4 = (const float4*)tables;  // [8][524288][16]
    float4* __restrict__ out4 = (float4*)out;
    const size_t out_base4 = (size_t)(b * TT + t0) * 128;     // float4 units

#pragma unroll
    for (int i = 0; i < 16; ++i) {
        const int flat  = i * 256 + tid;   // 0..4095, consecutive per lane
        const int d4    = flat & 15;       // float4 within row
        const int row   = flat >> 4;       // 0..255 = p*8 + table
        const int table = row & 7;
        const int p     = row >> 3;
        const unsigned idx = s_idx[p][table];
        const size_t src = ((size_t)table * BUCKETS + idx) * 16 + d4;
        out4[out_base4 + (size_t)flat] = tab4[src];
    }
}

extern "C" void kernel_launch(void* const* d_in, const int* in_sizes, int n_in,
                              void* d_out, int out_size, void* d_ws, size_t ws_size,
                              hipStream_t stream) {
    const int* tokens   = (const int*)d_in[0];
    const float* tables = (const float*)d_in[1];
    float* out          = (float*)d_out;

    const int blocks = (BB * TT) / POS_PER_BLOCK;  // 1024
    hashtables_kernel<<<blocks, 256, 0, stream>>>(tokens, tables, out);
}